// Round 11
// baseline (130.097 us; speedup 1.0000x reference)
//
#include <hip/hip_runtime.h>

#define EPSF 1e-20f

__device__ __forceinline__ float frcp(float x) { return __builtin_amdgcn_rcpf(x); }

// ===========================================================================
// Pipeline in (U, c) representation, U = x*c. LDS tiles are INTERLEAVED:
// each pixel is a float2 {c, d} (d = U). One b128 window read feeds both the
// denominator (conv c) and numerator (conv d) accumulators:
//   acc[co][p] : .x = den, .y = nom.
// ===========================================================================

struct CD8 { float2 v[8]; };
__device__ __forceinline__ CD8 load_cd8(const float2* p) {
    const float4* q = (const float4*)p;
    const float4 t0 = q[0], t1 = q[1], t2 = q[2], t3 = q[3];
    CD8 r;
    r.v[0] = make_float2(t0.x, t0.y); r.v[1] = make_float2(t0.z, t0.w);
    r.v[2] = make_float2(t1.x, t1.y); r.v[3] = make_float2(t1.z, t1.w);
    r.v[4] = make_float2(t2.x, t2.y); r.v[5] = make_float2(t2.z, t2.w);
    r.v[6] = make_float2(t3.x, t3.y); r.v[7] = make_float2(t3.z, t3.w);
    return r;
}
struct CD6 { float2 v[6]; };
__device__ __forceinline__ CD6 load_cd6(const float2* p) {
    const float4* q = (const float4*)p;
    const float4 t0 = q[0], t1 = q[1], t2 = q[2];
    CD6 r;
    r.v[0] = make_float2(t0.x, t0.y); r.v[1] = make_float2(t0.z, t0.w);
    r.v[2] = make_float2(t1.x, t1.y); r.v[3] = make_float2(t1.z, t1.w);
    r.v[4] = make_float2(t2.x, t2.y); r.v[5] = make_float2(t2.z, t2.w);
    return r;
}
__device__ __forceinline__ void fma2(float2& a, float w, float2 cd) {
    a.x = fmaf(w, cd.x, a.x);
    a.y = fmaf(w, cd.y, a.y);
}

// Conv core on interleaved LDS tile (row stride 72 px), window px [lw+2,lw+10).
template<int NCI, int CI0, int CINT, int K, int ROWS>
__device__ __forceinline__ void conv_core_i(const float2* __restrict__ s,
                                            const float* __restrict__ wgt,
                                            int lh, int lw,
                                            float2 acc[2][4])
{
    constexpr int JB = 2 - (K / 2);   // 0 for K=5, 1 for K=3
    #pragma unroll
    for (int kh = 0; kh < K; ++kh) {
        #pragma unroll
        for (int ci = 0; ci < NCI; ++ci) {
            const CD8 cd = load_cd8(s + (ci * ROWS + lh + kh) * 72 + lw + 2);
            #pragma unroll
            for (int kw = 0; kw < K; ++kw) {
                const float w0 = wgt[((0 * CINT + CI0 + ci) * K + kh) * K + kw];
                const float w1 = wgt[((1 * CINT + CI0 + ci) * K + kh) * K + kw];
                #pragma unroll
                for (int p = 0; p < 4; ++p) {
                    const int j = p + kw + JB;
                    fma2(acc[0][p], w0, cd.v[j]);
                    fma2(acc[1][p], w1, cd.v[j]);
                }
            }
        }
    }
}

// Half-res (2x-replicated) conv, interleaved [2][10][40] tiles, K=3.
template<int LO0>
__device__ __forceinline__ void conv_low_i(const float2* __restrict__ s_lo,
                                           const float* __restrict__ wgt,
                                           int lh, int lw,
                                           float2 acc[2][4])
{
    #pragma unroll
    for (int kh = 0; kh < 3; ++kh) {
        const int rel_r = ((lh + kh - 1) >> 1) + 1;
        #pragma unroll
        for (int lci = 0; lci < 2; ++lci) {
            const CD6 cd = load_cd6(s_lo + (lci * 10 + rel_r) * 40 + (lw >> 1) + 2);
            #pragma unroll
            for (int kw = 0; kw < 3; ++kw) {
                const float w0 = wgt[((0 * 4 + LO0 + lci) * 3 + kh) * 3 + kw];
                const float w1 = wgt[((1 * 4 + LO0 + lci) * 3 + kh) * 3 + kw];
                #pragma unroll
                for (int p = 0; p < 4; ++p) {
                    const int t = p + kw - 1;
                    const int jl = ((t < 0) ? -1 : (t >> 1)) + 2;
                    fma2(acc[0][p], w0, cd.v[jl]);
                    fma2(acc[1][p], w1, cd.v[jl]);
                }
            }
        }
    }
}

template<int CINT, int K>
__device__ __forceinline__ void nconv_epilogue_i(const float* __restrict__ wgt,
                                                 const float* __restrict__ bias,
                                                 float2 acc[2][4],
                                                 float4 uo[2], float4 co4[2])
{
    #pragma unroll
    for (int c = 0; c < 2; ++c) {
        float s = 0.f;
        for (int i = 0; i < CINT * K * K; ++i) s += wgt[c * CINT * K * K + i];
        const float is = 1.0f / s;
        const float bb = bias[c];
        #pragma unroll
        for (int p = 0; p < 4; ++p) {
            const float xo = acc[c][p].y * frcp(acc[c][p].x + EPSF) + bb;
            const float cv = acc[c][p].x * is;
            (&co4[c].x)[p] = cv;
            (&uo[c].x)[p]  = xo * cv;
        }
    }
}

// ===========================================================================
// NEW: fully-fused @512 encoder: enc1(1->2) -> enc2(2->2) -> enc3(2->2) +
// 2x2 pool. Tile 64x16. LDS union (52.2 KB, interleaved float2):
//   m1  [2][24][76]  rows [bh-4,bh+20) x cols [bw-6,bw+70)  (enc1 out)
//   in  [28][80]     rows [bh-6,bh+22) x cols [bw-8,bw+72)  (overlaid by m2)
//   m2  [2][20][72]  rows [bh-2,bh+18) x cols [bw-4,bw+68)  (enc2 out)
// enc2/enc1 windows are the aligned 8-px spans [4g, 4g+8).
// ===========================================================================
__global__ __launch_bounds__(256)
void enc123_fused(const float* __restrict__ x0, const float* __restrict__ c0,
                  const float* __restrict__ w1, const float* __restrict__ b1,
                  const float* __restrict__ w2, const float* __restrict__ b2,
                  const float* __restrict__ w3, const float* __restrict__ b3,
                  float* __restrict__ X1u, float* __restrict__ X1c,
                  float* __restrict__ p1u, float* __restrict__ p1c)
{
    __shared__ __align__(16) float2 smem[6528];
    float2* m1  = smem;           // 3648 f2
    float2* inb = smem + 3648;    // 2240 f2 (dead after enc1)
    float2* m2  = smem + 3648;    // 2880 f2 (overlays inb)

    const int tid = threadIdx.x;
    const int bw = blockIdx.x * 64;
    const int bh = blockIdx.y * 16;
    const int b  = blockIdx.z;

    // Stage input rows [bh-6, bh+22) x cols [bw-8, bw+72), {c, x*c}.
    const float4* x4 = (const float4*)x0;
    const float4* c4 = (const float4*)c0;
    for (int i = tid; i < 560; i += 256) {
        const int r = i / 20, k = i % 20;
        const int gh = bh - 6 + r;
        const int gw4 = (bw >> 2) - 2 + k;
        float4 xx = make_float4(0.f, 0.f, 0.f, 0.f);
        float4 cc = make_float4(0.f, 0.f, 0.f, 0.f);
        if ((unsigned)gh < 512u && (unsigned)gw4 < 128u) {
            const int a = (b << 16) + (gh << 7) + gw4;
            xx = x4[a];
            cc = c4[a];
        }
        float4* dst = (float4*)(inb + r * 80 + 4 * k);
        dst[0] = make_float4(cc.x, xx.x * cc.x, cc.y, xx.y * cc.y);
        dst[1] = make_float4(cc.z, xx.z * cc.z, cc.w, xx.w * cc.w);
    }

    float is1[2], is2[2];
    {
        float s0 = 0.f, s1 = 0.f;
        for (int i = 0; i < 25; ++i) { s0 += w1[i]; s1 += w1[25 + i]; }
        is1[0] = 1.0f / s0; is1[1] = 1.0f / s1;
        float t0 = 0.f, t1 = 0.f;
        for (int i = 0; i < 50; ++i) { t0 += w2[i]; t1 += w2[50 + i]; }
        is2[0] = 1.0f / t0; is2[1] = 1.0f / t1;
    }
    __syncthreads();

    // ---- enc1: 24 rows x 19 groups = 456 items (256 + 200).
    #pragma unroll
    for (int pass = 0; pass < 2; ++pass) {
        int r, g; bool active = true;
        if (pass == 0) { r = tid >> 4; g = tid & 15; }
        else {
            if (tid < 128) { r = 16 + (tid >> 4); g = tid & 15; }
            else if (tid < 200) { const int t = tid - 128; r = t / 3; g = 16 + t % 3; }
            else { active = false; r = 0; g = 0; }
        }
        if (active) {
            float2 acc[2][4];
            #pragma unroll
            for (int c = 0; c < 2; ++c)
                #pragma unroll
                for (int p = 0; p < 4; ++p) acc[c][p] = make_float2(0.f, 0.f);
            #pragma unroll
            for (int kh = 0; kh < 5; ++kh) {
                const CD8 cd = load_cd8(inb + (r + kh) * 80 + 4 * g);
                #pragma unroll
                for (int kw = 0; kw < 5; ++kw) {
                    const float wa = w1[kh * 5 + kw];
                    const float wb = w1[25 + kh * 5 + kw];
                    #pragma unroll
                    for (int p = 0; p < 4; ++p) {
                        fma2(acc[0][p], wa, cd.v[p + kw]);
                        fma2(acc[1][p], wb, cd.v[p + kw]);
                    }
                }
            }
            const int orow = bh - 4 + r;
            const bool rok = (unsigned)orow < 512u;
            #pragma unroll
            for (int c = 0; c < 2; ++c) {
                float cv[4], du[4];
                #pragma unroll
                for (int p = 0; p < 4; ++p) {
                    const int ocol = bw - 6 + 4 * g + p;
                    const bool ok = rok && (unsigned)ocol < 512u;
                    const float xo = acc[c][p].y * frcp(acc[c][p].x + EPSF) + b1[c];
                    const float v = acc[c][p].x * is1[c];
                    cv[p] = ok ? v : 0.f;
                    du[p] = ok ? xo * v : 0.f;
                }
                float4* dst = (float4*)(m1 + (c * 24 + r) * 76 + 4 * g);
                dst[0] = make_float4(cv[0], du[0], cv[1], du[1]);
                dst[1] = make_float4(cv[2], du[2], cv[3], du[3]);
            }
        }
    }
    __syncthreads();   // m1 complete; inb dead -> m2 may overlay

    // ---- enc2: 20 rows x 18 groups = 360 items (256 + 104).
    #pragma unroll
    for (int pass = 0; pass < 2; ++pass) {
        int r, g; bool active = true;
        if (pass == 0) { r = tid >> 4; g = tid & 15; }
        else {
            if (tid < 64) { r = 16 + (tid >> 4); g = tid & 15; }
            else if (tid < 104) { const int t = tid - 64; r = t >> 1; g = 16 + (t & 1); }
            else { active = false; r = 0; g = 0; }
        }
        if (active) {
            float2 acc[2][4];
            #pragma unroll
            for (int c = 0; c < 2; ++c)
                #pragma unroll
                for (int p = 0; p < 4; ++p) acc[c][p] = make_float2(0.f, 0.f);
            #pragma unroll
            for (int kh = 0; kh < 5; ++kh) {
                #pragma unroll
                for (int ci = 0; ci < 2; ++ci) {
                    const CD8 cd = load_cd8(m1 + (ci * 24 + r + kh) * 76 + 4 * g);
                    #pragma unroll
                    for (int kw = 0; kw < 5; ++kw) {
                        const float wa = w2[((0 * 2 + ci) * 5 + kh) * 5 + kw];
                        const float wb = w2[((1 * 2 + ci) * 5 + kh) * 5 + kw];
                        #pragma unroll
                        for (int p = 0; p < 4; ++p) {
                            fma2(acc[0][p], wa, cd.v[p + kw]);
                            fma2(acc[1][p], wb, cd.v[p + kw]);
                        }
                    }
                }
            }
            const int orow = bh - 2 + r;
            const bool rok = (unsigned)orow < 512u;
            #pragma unroll
            for (int c = 0; c < 2; ++c) {
                float cv[4], du[4];
                #pragma unroll
                for (int p = 0; p < 4; ++p) {
                    const int ocol = bw - 4 + 4 * g + p;
                    const bool ok = rok && (unsigned)ocol < 512u;
                    const float xo = acc[c][p].y * frcp(acc[c][p].x + EPSF) + b2[c];
                    const float v = acc[c][p].x * is2[c];
                    cv[p] = ok ? v : 0.f;
                    du[p] = ok ? xo * v : 0.f;
                }
                float4* dst = (float4*)(m2 + (c * 20 + r) * 72 + 4 * g);
                dst[0] = make_float4(cv[0], du[0], cv[1], du[1]);
                dst[1] = make_float4(cv[2], du[2], cv[3], du[3]);
            }
        }
    }
    __syncthreads();

    // ---- enc3 + pool.
    const int lh = tid >> 4;
    const int lw = (tid & 15) << 2;
    float2 acc[2][4];
    #pragma unroll
    for (int c = 0; c < 2; ++c)
        #pragma unroll
        for (int p = 0; p < 4; ++p) acc[c][p] = make_float2(0.f, 0.f);

    conv_core_i<2, 0, 2, 5, 20>(m2, w3, lh, lw, acc);

    float4 uo[2], co4[2];
    nconv_epilogue_i<2, 5>(w3, b3, acc, uo, co4);

    const int oh = bh + lh;
    #pragma unroll
    for (int c = 0; c < 2; ++c) {
        const int a = ((b * 2 + c) << 16) + (oh << 7) + ((bw + lw) >> 2);
        ((float4*)X1u)[a] = uo[c];
        ((float4*)X1c)[a] = co4[c];
    }

    // Pool overlay on m1 region (dead): [2][16][64] float2 {c, u}.
    __syncthreads();
    float2* pb = m1;
    #pragma unroll
    for (int c = 0; c < 2; ++c) {
        float2* row = pb + (c * 16 + lh) * 64 + lw;
        #pragma unroll
        for (int p = 0; p < 4; ++p)
            row[p] = make_float2((&co4[c].x)[p], (&uo[c].x)[p]);
    }
    __syncthreads();
    #pragma unroll
    for (int rep = 0; rep < 2; ++rep) {
        const int o = tid + rep * 256;
        const int ch = o >> 8;
        const int idx = o & 255;
        const int pr = idx >> 5;
        const int pcc = idx & 31;
        const float2* base = pb + (ch * 16 + 2 * pr) * 64 + 2 * pcc;
        const float2 a0 = base[0], a1 = base[1], a2 = base[64], a3 = base[65];
        float m = a0.x, g = a0.y;
        if (a1.x > m) { m = a1.x; g = a1.y; }
        if (a2.x > m) { m = a2.x; g = a2.y; }
        if (a3.x > m) { m = a3.x; g = a3.y; }
        const int pa = ((b * 2 + ch) << 16) + (((bh >> 1) + pr) << 8) + (bw >> 1) + pcc;
        p1u[pa] = g * 0.25f;
        p1c[pa] = m * 0.25f;
    }
}

// ===========================================================================
// Fused enc4 + enc5 (both CIN=2, 5x5) @256 with fused 2x2 pool -> @128.
// ===========================================================================
__global__ __launch_bounds__(256)
void enc45_fused(const float* __restrict__ inU, const float* __restrict__ inC,
                 const float* __restrict__ wA, const float* __restrict__ bA,
                 const float* __restrict__ wB, const float* __restrict__ bB,
                 float* __restrict__ uout, float* __restrict__ cout,
                 float* __restrict__ poolU, float* __restrict__ poolC)
{
    __shared__ __align__(16) float2 in_cd[2][24][84];
    __shared__ __align__(16) float2 mid_cd[2][20][72];

    const int tid = threadIdx.x;
    const int bw = blockIdx.x * 64;
    const int bh = blockIdx.y * 16;
    const int b  = blockIdx.z;

    const float4* U4 = (const float4*)inU;
    const float4* C4 = (const float4*)inC;
    for (int i = tid; i < 960; i += 256) {
        const int ci = i / 480;
        const int r = (i / 20) % 24, k = i % 20;
        const int gh = bh - 4 + r;
        const int gw4 = (bw >> 2) - 2 + k;
        float4 dd = make_float4(0.f, 0.f, 0.f, 0.f);
        float4 cc = make_float4(0.f, 0.f, 0.f, 0.f);
        if ((unsigned)gh < 256u && (unsigned)gw4 < 64u) {
            const int a = ((b * 2 + ci) << 14) + (gh << 6) + gw4;
            dd = U4[a];
            cc = C4[a];
        }
        float4* dst = (float4*)&in_cd[ci][r][4 * k];
        dst[0] = make_float4(cc.x, dd.x, cc.y, dd.y);
        dst[1] = make_float4(cc.z, dd.z, cc.w, dd.w);
    }

    float isA0, isA1;
    {
        float s0 = 0.f, s1 = 0.f;
        for (int i = 0; i < 50; ++i) { s0 += wA[i]; s1 += wA[50 + i]; }
        isA0 = 1.0f / s0;
        isA1 = 1.0f / s1;
    }
    __syncthreads();

    // Stage A: 20 rows x 18 groups = 360 items (256 + 104), CIN=2.
    #pragma unroll
    for (int pass = 0; pass < 2; ++pass) {
        int r, g;
        bool active = true;
        if (pass == 0) { r = tid >> 4; g = tid & 15; }
        else {
            if (tid < 64) { r = 16 + (tid >> 4); g = tid & 15; }
            else if (tid < 104) { const int t = tid - 64; r = t >> 1; g = 16 + (t & 1); }
            else { active = false; r = 0; g = 0; }
        }
        if (active) {
            float2 acc[2][4];
            #pragma unroll
            for (int c = 0; c < 2; ++c)
                #pragma unroll
                for (int p = 0; p < 4; ++p) acc[c][p] = make_float2(0.f, 0.f);
            #pragma unroll
            for (int kh = 0; kh < 5; ++kh) {
                #pragma unroll
                for (int ci = 0; ci < 2; ++ci) {
                    const CD8 cd = load_cd8(&in_cd[ci][r + kh][4 * g + 2]);
                    #pragma unroll
                    for (int kw = 0; kw < 5; ++kw) {
                        const float w0 = wA[((0 * 2 + ci) * 5 + kh) * 5 + kw];
                        const float w1 = wA[((1 * 2 + ci) * 5 + kh) * 5 + kw];
                        #pragma unroll
                        for (int p = 0; p < 4; ++p) {
                            fma2(acc[0][p], w0, cd.v[p + kw]);
                            fma2(acc[1][p], w1, cd.v[p + kw]);
                        }
                    }
                }
            }
            const int orow = bh + r - 2;
            const bool rok = (unsigned)orow < 256u;
            #pragma unroll
            for (int c = 0; c < 2; ++c) {
                const float is = (c == 0) ? isA0 : isA1;
                float cv[4], du[4];
                #pragma unroll
                for (int p = 0; p < 4; ++p) {
                    const int ocol = bw + 4 * g - 4 + p;
                    const bool ok = rok && (unsigned)ocol < 256u;
                    const float xo = acc[c][p].y * frcp(acc[c][p].x + EPSF) + bA[c];
                    const float v = acc[c][p].x * is;
                    cv[p] = ok ? v : 0.f;
                    du[p] = ok ? xo * v : 0.f;
                }
                float4* dst = (float4*)&mid_cd[c][r][4 * g];
                dst[0] = make_float4(cv[0], du[0], cv[1], du[1]);
                dst[1] = make_float4(cv[2], du[2], cv[3], du[3]);
            }
        }
    }
    __syncthreads();

    // Stage B + pool.
    const int lh = tid >> 4;
    const int lw = (tid & 15) << 2;
    float2 acc[2][4];
    #pragma unroll
    for (int c = 0; c < 2; ++c)
        #pragma unroll
        for (int p = 0; p < 4; ++p) acc[c][p] = make_float2(0.f, 0.f);

    conv_core_i<2, 0, 2, 5, 20>(&mid_cd[0][0][0], wB, lh, lw, acc);

    float4 uo[2], co4[2];
    nconv_epilogue_i<2, 5>(wB, bB, acc, uo, co4);

    const int oh = bh + lh;
    #pragma unroll
    for (int c = 0; c < 2; ++c) {
        const int a = ((b * 2 + c) << 14) + (oh << 6) + ((bw + lw) >> 2);
        ((float4*)uout)[a] = uo[c];
        ((float4*)cout)[a] = co4[c];
    }

    // Fused 2x2 pool via interleaved overlay on mid_cd: {c, u} per px.
    __syncthreads();
    float2* pb = &mid_cd[0][0][0];   // [2][16][64] float2
    #pragma unroll
    for (int c = 0; c < 2; ++c) {
        float2* row = pb + (c * 16 + lh) * 64 + lw;
        #pragma unroll
        for (int p = 0; p < 4; ++p)
            row[p] = make_float2((&co4[c].x)[p], (&uo[c].x)[p]);
    }
    __syncthreads();
    #pragma unroll
    for (int rep = 0; rep < 2; ++rep) {
        const int o = tid + rep * 256;
        const int ch = o >> 8;
        const int idx = o & 255;
        const int pr = idx >> 5;
        const int pcc = idx & 31;
        const float2* base = pb + (ch * 16 + 2 * pr) * 64 + 2 * pcc;
        const float2 a0 = base[0], a1 = base[1], a2 = base[64], a3 = base[65];
        float m = a0.x, g = a0.y;
        if (a1.x > m) { m = a1.x; g = a1.y; }
        if (a2.x > m) { m = a2.x; g = a2.y; }
        if (a3.x > m) { m = a3.x; g = a3.y; }
        const int pa = ((b * 2 + ch) << 14) + (((bh >> 1) + pr) << 7) + (bw >> 1) + pcc;
        poolU[pa] = g * 0.25f;
        poolC[pa] = m * 0.25f;
    }
}

// ===========================================================================
// Mid kernel: whole @128/@64 sub-net per 64x16 tile @128 (interleaved).
// ===========================================================================
__global__ __launch_bounds__(256)
void mid_kern(const float* __restrict__ p2U, const float* __restrict__ p2C,
              const float* __restrict__ w2, const float* __restrict__ b2,
              const float* __restrict__ w4, const float* __restrict__ b4,
              float* __restrict__ x34U, float* __restrict__ x34C)
{
    __shared__ __align__(16) float2 sp_cd[2][32][88];
    __shared__ __align__(16) float2 sx3_cd[2][28][80];
    __shared__ __align__(16) float2 sp3_cd[2][14][48];
    __shared__ __align__(16) float2 sx4_cd[2][10][40];

    const int tid = threadIdx.x;
    const int bw = blockIdx.x * 64;
    const int bh = blockIdx.y * 16;
    const int b = blockIdx.z;

    const float4* U4 = (const float4*)p2U;
    const float4* C4 = (const float4*)p2C;
    for (int i = tid; i < 2 * 32 * 22; i += 256) {
        const int ci = i / 704;
        const int r  = (i / 22) % 32;
        const int cf = i % 22;
        const int gh = bh - 8 + r;
        const int gw4 = (bw >> 2) - 3 + cf;
        float4 dd = make_float4(0.f, 0.f, 0.f, 0.f);
        float4 cc = make_float4(0.f, 0.f, 0.f, 0.f);
        if ((unsigned)gh < 128u && (unsigned)gw4 < 32u) {
            const int a = ((b * 2 + ci) << 12) + (gh << 5) + gw4;
            dd = U4[a];
            cc = C4[a];
        }
        float4* dst = (float4*)&sp_cd[ci][r][cf * 4];
        dst[0] = make_float4(cc.x, dd.x, cc.y, dd.y);
        dst[1] = make_float4(cc.z, dd.z, cc.w, dd.w);
    }
    __syncthreads();

    {
        float s2[2];
        #pragma unroll
        for (int c = 0; c < 2; ++c) {
            float s = 0.f;
            for (int i = 0; i < 50; ++i) s += w2[c * 50 + i];
            s2[c] = 1.0f / s;
        }
        for (int s = tid; s < 560; s += 256) {
            const int r = s / 20;
            const int g = s % 20;
            float2 acc[2][4];
            #pragma unroll
            for (int c = 0; c < 2; ++c)
                #pragma unroll
                for (int p = 0; p < 4; ++p) acc[c][p] = make_float2(0.f, 0.f);
            #pragma unroll
            for (int kh = 0; kh < 5; ++kh) {
                #pragma unroll
                for (int ci = 0; ci < 2; ++ci) {
                    const CD8 cd = load_cd8(&sp_cd[ci][r + kh][4 * g + 2]);
                    #pragma unroll
                    for (int kw = 0; kw < 5; ++kw) {
                        const float w0 = w2[((0 * 2 + ci) * 5 + kh) * 5 + kw];
                        const float w1 = w2[((1 * 2 + ci) * 5 + kh) * 5 + kw];
                        #pragma unroll
                        for (int p = 0; p < 4; ++p) {
                            fma2(acc[0][p], w0, cd.v[p + kw]);
                            fma2(acc[1][p], w1, cd.v[p + kw]);
                        }
                    }
                }
            }
            const int orow = bh - 6 + r;
            const bool rok = (unsigned)orow < 128u;
            #pragma unroll
            for (int c = 0; c < 2; ++c) {
                float cv[4], du[4];
                #pragma unroll
                for (int p = 0; p < 4; ++p) {
                    const int ocol = bw - 8 + 4 * g + p;
                    const bool ok = rok && (unsigned)ocol < 128u;
                    const float xo = acc[c][p].y * frcp(acc[c][p].x + EPSF) + b2[c];
                    const float v = acc[c][p].x * s2[c];
                    cv[p] = ok ? v : 0.f;
                    du[p] = ok ? xo * v : 0.f;
                }
                float4* dst = (float4*)&sx3_cd[c][r][4 * g];
                dst[0] = make_float4(cv[0], du[0], cv[1], du[1]);
                dst[1] = make_float4(cv[2], du[2], cv[3], du[3]);
            }
        }
    }
    __syncthreads();

    for (int i = tid; i < 2 * 14 * 48; i += 256) {
        const int ch = i / 672;
        const int r  = (i / 48) % 14;
        const int c  = i % 48;
        const int R = (bh >> 1) - 3 + r;
        const int C = (bw >> 1) - 8 + c;
        float g = 0.f, m = 0.f;
        if (c >= 4 && c < 44 && (unsigned)R < 64u && (unsigned)C < 64u) {
            const int xr = 2 * r, xc = 2 * c - 8;
            const float2 a0 = sx3_cd[ch][xr][xc],     a1 = sx3_cd[ch][xr][xc + 1];
            const float2 a2 = sx3_cd[ch][xr + 1][xc], a3 = sx3_cd[ch][xr + 1][xc + 1];
            m = a0.x; g = a0.y;
            if (a1.x > m) { m = a1.x; g = a1.y; }
            if (a2.x > m) { m = a2.x; g = a2.y; }
            if (a3.x > m) { m = a3.x; g = a3.y; }
            g *= 0.25f; m *= 0.25f;
        }
        sp3_cd[ch][r][c] = make_float2(m, g);
    }
    __syncthreads();

    {
        float s2[2];
        #pragma unroll
        for (int c = 0; c < 2; ++c) {
            float s = 0.f;
            for (int i = 0; i < 50; ++i) s += w2[c * 50 + i];
            s2[c] = 1.0f / s;
        }
        for (int s = tid; s < 100; s += 256) {
            const int r = s / 10;
            const int g = s % 10;
            float2 acc[2][4];
            #pragma unroll
            for (int c = 0; c < 2; ++c)
                #pragma unroll
                for (int p = 0; p < 4; ++p) acc[c][p] = make_float2(0.f, 0.f);
            #pragma unroll
            for (int kh = 0; kh < 5; ++kh) {
                #pragma unroll
                for (int ci = 0; ci < 2; ++ci) {
                    const CD8 cd = load_cd8(&sp3_cd[ci][r + kh][4 * g + 2]);
                    #pragma unroll
                    for (int kw = 0; kw < 5; ++kw) {
                        const float w0 = w2[((0 * 2 + ci) * 5 + kh) * 5 + kw];
                        const float w1 = w2[((1 * 2 + ci) * 5 + kh) * 5 + kw];
                        #pragma unroll
                        for (int p = 0; p < 4; ++p) {
                            fma2(acc[0][p], w0, cd.v[p + kw]);
                            fma2(acc[1][p], w1, cd.v[p + kw]);
                        }
                    }
                }
            }
            const int orow = (bh >> 1) - 1 + r;
            const bool rok = (unsigned)orow < 64u;
            #pragma unroll
            for (int c = 0; c < 2; ++c) {
                float cv[4], du[4];
                #pragma unroll
                for (int p = 0; p < 4; ++p) {
                    const int ocol = (bw >> 1) - 4 + 4 * g + p;
                    const bool ok = rok && (unsigned)ocol < 64u;
                    const float xo = acc[c][p].y * frcp(acc[c][p].x + EPSF) + b2[c];
                    const float v = acc[c][p].x * s2[c];
                    cv[p] = ok ? v : 0.f;
                    du[p] = ok ? xo * v : 0.f;
                }
                float4* dst = (float4*)&sx4_cd[c][r][4 * g];
                dst[0] = make_float4(cv[0], du[0], cv[1], du[1]);
                dst[1] = make_float4(cv[2], du[2], cv[3], du[3]);
            }
        }
    }
    __syncthreads();

    {
        const int lh = tid >> 4;
        const int lw = (tid & 15) << 2;
        float2 acc[2][4];
        #pragma unroll
        for (int c = 0; c < 2; ++c)
            #pragma unroll
            for (int p = 0; p < 4; ++p) acc[c][p] = make_float2(0.f, 0.f);

        // skip conv over sx3 (tile row0 = bh-6, col0 = bw-8): taps at px
        // lw+7..lw+13 -> load px [lw+6, lw+14), index j = p+kw+1.
        #pragma unroll
        for (int kh = 0; kh < 3; ++kh) {
            #pragma unroll
            for (int ci = 0; ci < 2; ++ci) {
                const CD8 cd = load_cd8(&sx3_cd[ci][lh + kh + 5][lw + 6]);
                #pragma unroll
                for (int kw = 0; kw < 3; ++kw) {
                    const float w0 = w4[((0 * 4 + ci) * 3 + kh) * 3 + kw];
                    const float w1 = w4[((1 * 4 + ci) * 3 + kh) * 3 + kw];
                    #pragma unroll
                    for (int p = 0; p < 4; ++p) {
                        const int j = p + kw + 1;
                        fma2(acc[0][p], w0, cd.v[j]);
                        fma2(acc[1][p], w1, cd.v[j]);
                    }
                }
            }
        }
        conv_low_i<2>(&sx4_cd[0][0][0], w4, lh, lw, acc);

        float4 uo[2], co4[2];
        nconv_epilogue_i<4, 3>(w4, b4, acc, uo, co4);
        #pragma unroll
        for (int c = 0; c < 2; ++c) {
            const int a = ((b * 2 + c) << 12) + ((bh + lh) << 5) + ((bw + lw) >> 2);
            ((float4*)x34U)[a] = uo[c];
            ((float4*)x34C)[a] = co4[c];
        }
    }
}

// ===========================================================================
// Decoder cat-nconv, interleaved; optional fused final 1x1 -> d_out.
// ===========================================================================
template<bool UP_FIRST, int LOGHW, bool FINAL>
__global__ __launch_bounds__(256)
void nconv_cat_tiled(const float* __restrict__ skU, const float* __restrict__ skC,
                     const float* __restrict__ loU, const float* __restrict__ loC,
                     const float* __restrict__ wgt, const float* __restrict__ bias,
                     float* __restrict__ uout, float* __restrict__ cout,
                     const float* __restrict__ w7, const float* __restrict__ b7)
{
    constexpr int HW = 1 << LOGHW;
    constexpr int HWL = HW >> 1;
    constexpr int TH = 16;
    constexpr int ROWS = TH + 2;
    constexpr int NC4 = 18;
    constexpr int SK0 = UP_FIRST ? 2 : 0;
    constexpr int LO0 = UP_FIRST ? 0 : 2;
    __shared__ __align__(16) float2 s_cd[2][ROWS][72];
    __shared__ __align__(16) float2 lo_cd[2][10][40];

    const int tid = threadIdx.x;
    const int base_w = blockIdx.x * 64;
    const int base_h = blockIdx.y * TH;
    const int b = blockIdx.z;

    constexpr int SLOTS = 2 * ROWS * NC4;
    const float4* sU4 = (const float4*)skU;
    const float4* sC4 = (const float4*)skC;
    for (int i = tid; i < SLOTS; i += 256) {
        const int ci = i / (ROWS * NC4);
        const int r  = (i / NC4) % ROWS;
        const int cf = i % NC4;
        const int gh = base_h - 1 + r;
        const int gw4 = (base_w >> 2) + cf - 1;
        float4 dd = make_float4(0.f, 0.f, 0.f, 0.f);
        float4 cc = make_float4(0.f, 0.f, 0.f, 0.f);
        if ((unsigned)gh < (unsigned)HW && (unsigned)gw4 < (unsigned)(HW >> 2)) {
            const int a = ((b * 2 + ci) << (2 * LOGHW - 2)) + (gh << (LOGHW - 2)) + gw4;
            dd = sU4[a];
            cc = sC4[a];
        }
        float4* dst = (float4*)&s_cd[ci][r][cf * 4];
        dst[0] = make_float4(cc.x, dd.x, cc.y, dd.y);
        dst[1] = make_float4(cc.z, dd.z, cc.w, dd.w);
    }
    constexpr int LO_SLOTS = 2 * 10 * 10;
    const int lo_r0 = (base_h >> 1) - 1;
    const int lo_c4_0 = (base_w >> 3) - 1;
    const float4* lU4 = (const float4*)loU;
    const float4* lC4 = (const float4*)loC;
    for (int i = tid; i < LO_SLOTS; i += 256) {
        const int ci = i / 100;
        const int r  = (i / 10) % 10;
        const int cf = i % 10;
        const int gr = lo_r0 + r;
        const int gc4 = lo_c4_0 + cf;
        float4 dd = make_float4(0.f, 0.f, 0.f, 0.f);
        float4 cc = make_float4(0.f, 0.f, 0.f, 0.f);
        if ((unsigned)gr < (unsigned)HWL && (unsigned)gc4 < (unsigned)(HWL >> 2)) {
            const int a = ((b * 2 + ci) << (2 * (LOGHW - 1) - 2)) + (gr << (LOGHW - 3)) + gc4;
            dd = lU4[a];
            cc = lC4[a];
        }
        float4* dst = (float4*)&lo_cd[ci][r][cf * 4];
        dst[0] = make_float4(cc.x, dd.x, cc.y, dd.y);
        dst[1] = make_float4(cc.z, dd.z, cc.w, dd.w);
    }
    __syncthreads();

    const int lh = tid >> 4;
    const int lw = (tid & 15) << 2;
    float2 acc[2][4];
    #pragma unroll
    for (int c = 0; c < 2; ++c)
        #pragma unroll
        for (int p = 0; p < 4; ++p) acc[c][p] = make_float2(0.f, 0.f);

    conv_core_i<2, SK0, 4, 3, ROWS>(&s_cd[0][0][0], wgt, lh, lw, acc);
    conv_low_i<LO0>(&lo_cd[0][0][0], wgt, lh, lw, acc);

    float4 uo[2], co4[2];
    nconv_epilogue_i<4, 3>(wgt, bias, acc, uo, co4);

    const int oh = base_h + lh;
    if (FINAL) {
        const float w70 = w7[0], w71 = w7[1], bb7 = b7[0];
        const float inv = frcp(w70 + w71);
        float4 xo4, cc4;
        #pragma unroll
        for (int p = 0; p < 4; ++p) {
            const float d1 = w70 * (&co4[0].x)[p] + w71 * (&co4[1].x)[p];
            (&xo4.x)[p] = (w70 * (&uo[0].x)[p] + w71 * (&uo[1].x)[p]) * frcp(d1 + EPSF) + bb7;
            (&cc4.x)[p] = d1 * inv;
        }
        const int a = (b << (2 * LOGHW - 2)) + (oh << (LOGHW - 2)) + ((base_w + lw) >> 2);
        ((float4*)uout)[a] = xo4;
        ((float4*)uout)[(1 << 19) + a] = cc4;
    } else {
        #pragma unroll
        for (int c = 0; c < 2; ++c) {
            const int a = ((b * 2 + c) << (2 * LOGHW - 2)) + (oh << (LOGHW - 2)) + ((base_w + lw) >> 2);
            ((float4*)uout)[a] = uo[c];
            ((float4*)cout)[a] = co4[c];
        }
    }
}

// ---------------------------------------------------------------------------
extern "C" void kernel_launch(void* const* d_in, const int* in_sizes, int n_in,
                              void* d_out, int out_size, void* d_ws, size_t ws_size,
                              hipStream_t stream) {
    (void)in_sizes; (void)n_in; (void)out_size; (void)ws_size;
    const float* x0 = (const float*)d_in[0];
    const float* c0 = (const float*)d_in[1];
    const float* w1 = (const float*)d_in[2];  const float* b1 = (const float*)d_in[3];
    const float* w2 = (const float*)d_in[4];  const float* b2 = (const float*)d_in[5];
    const float* w3 = (const float*)d_in[6];  const float* b3 = (const float*)d_in[7];
    const float* w4 = (const float*)d_in[8];  const float* b4 = (const float*)d_in[9];
    const float* w5 = (const float*)d_in[10]; const float* b5 = (const float*)d_in[11];
    const float* w6 = (const float*)d_in[12]; const float* b6 = (const float*)d_in[13];
    const float* w7 = (const float*)d_in[14]; const float* b7 = (const float*)d_in[15];

    float* ws = (float*)d_ws;
    const size_t S512 = 8ull * 2 * 512 * 512;
    const size_t S256 = 8ull * 2 * 256 * 256;
    const size_t S128 = 8ull * 2 * 128 * 128;

    float* X1x = ws;            float* X1c = ws + S512;
    float* Ax  = ws + 2 * S512;
    float* Bx  = ws + 4 * S512;
    float* x23x = Ax;               float* x23c = Ax + S256;
    float* x2x  = Ax + 2 * S256;    float* x2c  = Ax + 3 * S256;
    float* p1x  = Ax + 4 * S256;    float* p1c  = Ax + 5 * S256;
    float* p2x  = Bx + 2 * S128;    float* p2c  = Bx + 3 * S128;
    float* x34x = Bx + 4 * S128;    float* x34c = Bx + 5 * S128;

    // K1: whole @512 encoder (enc1+enc2+enc3+pool) -> X1 (skip), p1 @256
    enc123_fused<<<dim3(8, 32, 8), 256, 0, stream>>>(
        x0, c0, w1, b1, w2, b2, w3, b3, X1x, X1c, p1x, p1c);
    // K2: fused enc4+enc5 @256 + pool -> x2 @256, p2 @128
    enc45_fused<<<dim3(4, 16, 8), 256, 0, stream>>>(
        p1x, p1c, w2, b2, w3, b3, x2x, x2c, p2x, p2c);
    // K3: whole @128/@64 sub-net -> x34 @128
    mid_kern<<<dim3(2, 8, 8), 256, 0, stream>>>(
        p2x, p2c, w2, b2, w4, b4, x34x, x34c);
    // K4: cat @256 -> x23
    nconv_cat_tiled<false, 8, false><<<dim3(4, 16, 8), 256, 0, stream>>>(
        x2x, x2c, x34x, x34c, w5, b5, x23x, x23c, nullptr, nullptr);
    // K5: cat @512 + final 1x1 -> d_out
    nconv_cat_tiled<true, 9, true><<<dim3(8, 32, 8), 256, 0, stream>>>(
        X1x, X1c, x23x, x23c, w6, b6, (float*)d_out, nullptr, w7, b7);
}

// Round 12
// 113.578 us; speedup vs baseline: 1.1454x; 1.1454x over previous
//
#include <hip/hip_runtime.h>

#define EPSF 1e-20f

typedef float v2f __attribute__((ext_vector_type(2)));

__device__ __forceinline__ float frcp(float x) { return __builtin_amdgcn_rcpf(x); }

// ===========================================================================
// Pipeline in (U, c) representation, U = x*c. LDS tiles are INTERLEAVED:
// each pixel is a float2 {c, d} (d = U). One b128 window read feeds both
// accumulators; acc[co][p] is a v2f {den, nom} updated with v_pk_fma_f32.
// ===========================================================================

struct CD8 { v2f v[8]; };
__device__ __forceinline__ CD8 load_cd8(const float2* p) {
    const float4* q = (const float4*)p;
    const float4 t0 = q[0], t1 = q[1], t2 = q[2], t3 = q[3];
    CD8 r;
    r.v[0] = (v2f){t0.x, t0.y}; r.v[1] = (v2f){t0.z, t0.w};
    r.v[2] = (v2f){t1.x, t1.y}; r.v[3] = (v2f){t1.z, t1.w};
    r.v[4] = (v2f){t2.x, t2.y}; r.v[5] = (v2f){t2.z, t2.w};
    r.v[6] = (v2f){t3.x, t3.y}; r.v[7] = (v2f){t3.z, t3.w};
    return r;
}
struct CD6 { v2f v[6]; };
__device__ __forceinline__ CD6 load_cd6(const float2* p) {
    const float4* q = (const float4*)p;
    const float4 t0 = q[0], t1 = q[1], t2 = q[2];
    CD6 r;
    r.v[0] = (v2f){t0.x, t0.y}; r.v[1] = (v2f){t0.z, t0.w};
    r.v[2] = (v2f){t1.x, t1.y}; r.v[3] = (v2f){t1.z, t1.w};
    r.v[4] = (v2f){t2.x, t2.y}; r.v[5] = (v2f){t2.z, t2.w};
    return r;
}
__device__ __forceinline__ void fma2(v2f& a, float w, v2f cd) {
    a = __builtin_elementwise_fma((v2f){w, w}, cd, a);
}

// Conv core on interleaved LDS tile (row stride 72 px), window px [lw+2,lw+10).
template<int NCI, int CI0, int CINT, int K, int ROWS>
__device__ __forceinline__ void conv_core_i(const float2* __restrict__ s,
                                            const float* __restrict__ wgt,
                                            int lh, int lw,
                                            v2f acc[2][4])
{
    constexpr int JB = 2 - (K / 2);   // 0 for K=5, 1 for K=3
    #pragma unroll
    for (int kh = 0; kh < K; ++kh) {
        #pragma unroll
        for (int ci = 0; ci < NCI; ++ci) {
            const CD8 cd = load_cd8(s + (ci * ROWS + lh + kh) * 72 + lw + 2);
            #pragma unroll
            for (int kw = 0; kw < K; ++kw) {
                const float w0 = wgt[((0 * CINT + CI0 + ci) * K + kh) * K + kw];
                const float w1 = wgt[((1 * CINT + CI0 + ci) * K + kh) * K + kw];
                #pragma unroll
                for (int p = 0; p < 4; ++p) {
                    const int j = p + kw + JB;
                    fma2(acc[0][p], w0, cd.v[j]);
                    fma2(acc[1][p], w1, cd.v[j]);
                }
            }
        }
    }
}

// Half-res (2x-replicated) conv, interleaved [2][10][40] tiles, K=3.
template<int LO0>
__device__ __forceinline__ void conv_low_i(const float2* __restrict__ s_lo,
                                           const float* __restrict__ wgt,
                                           int lh, int lw,
                                           v2f acc[2][4])
{
    #pragma unroll
    for (int kh = 0; kh < 3; ++kh) {
        const int rel_r = ((lh + kh - 1) >> 1) + 1;
        #pragma unroll
        for (int lci = 0; lci < 2; ++lci) {
            const CD6 cd = load_cd6(s_lo + (lci * 10 + rel_r) * 40 + (lw >> 1) + 2);
            #pragma unroll
            for (int kw = 0; kw < 3; ++kw) {
                const float w0 = wgt[((0 * 4 + LO0 + lci) * 3 + kh) * 3 + kw];
                const float w1 = wgt[((1 * 4 + LO0 + lci) * 3 + kh) * 3 + kw];
                #pragma unroll
                for (int p = 0; p < 4; ++p) {
                    const int t = p + kw - 1;
                    const int jl = ((t < 0) ? -1 : (t >> 1)) + 2;
                    fma2(acc[0][p], w0, cd.v[jl]);
                    fma2(acc[1][p], w1, cd.v[jl]);
                }
            }
        }
    }
}

template<int CINT, int K>
__device__ __forceinline__ void nconv_epilogue_i(const float* __restrict__ wgt,
                                                 const float* __restrict__ bias,
                                                 v2f acc[2][4],
                                                 float4 uo[2], float4 co4[2])
{
    #pragma unroll
    for (int c = 0; c < 2; ++c) {
        float s = 0.f;
        for (int i = 0; i < CINT * K * K; ++i) s += wgt[c * CINT * K * K + i];
        const float is = 1.0f / s;
        const float bb = bias[c];
        #pragma unroll
        for (int p = 0; p < 4; ++p) {
            const float xo = acc[c][p].y * frcp(acc[c][p].x + EPSF) + bb;
            const float cv = acc[c][p].x * is;
            (&co4[c].x)[p] = cv;
            (&uo[c].x)[p]  = xo * cv;
        }
    }
}

// ===========================================================================
// Fused enc1(CIN=1) + enc2(CIN=2) @512, tile 64x16, interleaved LDS.
// ===========================================================================
__global__ __launch_bounds__(256)
void enc12_fused(const float* __restrict__ x0, const float* __restrict__ c0,
                 const float* __restrict__ wA, const float* __restrict__ bA,
                 const float* __restrict__ wB, const float* __restrict__ bB,
                 float* __restrict__ uout, float* __restrict__ cout)
{
    __shared__ __align__(16) float2 in_cd[24][84];
    __shared__ __align__(16) float2 mid_cd[2][20][72];

    const int tid = threadIdx.x;
    const int bw = blockIdx.x * 64;
    const int bh = blockIdx.y * 16;
    const int b  = blockIdx.z;

    const float4* x4 = (const float4*)x0;
    const float4* c4 = (const float4*)c0;
    for (int i = tid; i < 480; i += 256) {
        const int r = i / 20, k = i % 20;
        const int gh = bh - 4 + r;
        const int gw4 = (bw >> 2) - 2 + k;
        float4 xx = make_float4(0.f, 0.f, 0.f, 0.f);
        float4 cc = make_float4(0.f, 0.f, 0.f, 0.f);
        if ((unsigned)gh < 512u && (unsigned)gw4 < 128u) {
            const int a = (b << 16) + (gh << 7) + gw4;
            xx = x4[a];
            cc = c4[a];
        }
        float4* dst = (float4*)&in_cd[r][4 * k];
        dst[0] = make_float4(cc.x, xx.x * cc.x, cc.y, xx.y * cc.y);
        dst[1] = make_float4(cc.z, xx.z * cc.z, cc.w, xx.w * cc.w);
    }

    float isA0, isA1;
    {
        float s0 = 0.f, s1 = 0.f;
        for (int i = 0; i < 25; ++i) { s0 += wA[i]; s1 += wA[25 + i]; }
        isA0 = 1.0f / s0;
        isA1 = 1.0f / s1;
    }
    __syncthreads();

    // Stage A: 20 rows x 18 groups = 360 items (256 + 104).
    #pragma unroll
    for (int pass = 0; pass < 2; ++pass) {
        int r, g;
        bool active = true;
        if (pass == 0) { r = tid >> 4; g = tid & 15; }
        else {
            if (tid < 64) { r = 16 + (tid >> 4); g = tid & 15; }
            else if (tid < 104) { const int t = tid - 64; r = t >> 1; g = 16 + (t & 1); }
            else { active = false; r = 0; g = 0; }
        }
        if (active) {
            v2f acc[2][4];
            #pragma unroll
            for (int c = 0; c < 2; ++c)
                #pragma unroll
                for (int p = 0; p < 4; ++p) acc[c][p] = (v2f){0.f, 0.f};
            #pragma unroll
            for (int kh = 0; kh < 5; ++kh) {
                const CD8 cd = load_cd8(&in_cd[r + kh][4 * g + 2]);
                #pragma unroll
                for (int kw = 0; kw < 5; ++kw) {
                    const float w0 = wA[kh * 5 + kw];
                    const float w1 = wA[25 + kh * 5 + kw];
                    #pragma unroll
                    for (int p = 0; p < 4; ++p) {
                        fma2(acc[0][p], w0, cd.v[p + kw]);
                        fma2(acc[1][p], w1, cd.v[p + kw]);
                    }
                }
            }
            const int orow = bh + r - 2;
            const bool rok = (unsigned)orow < 512u;
            #pragma unroll
            for (int c = 0; c < 2; ++c) {
                const float is = (c == 0) ? isA0 : isA1;
                float cv[4], du[4];
                #pragma unroll
                for (int p = 0; p < 4; ++p) {
                    const int ocol = bw + 4 * g - 4 + p;
                    const bool ok = rok && (unsigned)ocol < 512u;
                    const float xo = acc[c][p].y * frcp(acc[c][p].x + EPSF) + bA[c];
                    const float v = acc[c][p].x * is;
                    cv[p] = ok ? v : 0.f;
                    du[p] = ok ? xo * v : 0.f;
                }
                float4* dst = (float4*)&mid_cd[c][r][4 * g];
                dst[0] = make_float4(cv[0], du[0], cv[1], du[1]);
                dst[1] = make_float4(cv[2], du[2], cv[3], du[3]);
            }
        }
    }
    __syncthreads();

    const int lh = tid >> 4;
    const int lw = (tid & 15) << 2;
    v2f acc[2][4];
    #pragma unroll
    for (int c = 0; c < 2; ++c)
        #pragma unroll
        for (int p = 0; p < 4; ++p) acc[c][p] = (v2f){0.f, 0.f};

    conv_core_i<2, 0, 2, 5, 20>(&mid_cd[0][0][0], wB, lh, lw, acc);

    float4 uo[2], co4[2];
    nconv_epilogue_i<2, 5>(wB, bB, acc, uo, co4);

    const int oh = bh + lh;
    #pragma unroll
    for (int c = 0; c < 2; ++c) {
        const int a = ((b * 2 + c) << 16) + (oh << 7) + ((bw + lw) >> 2);
        ((float4*)uout)[a] = uo[c];
        ((float4*)cout)[a] = co4[c];
    }
}

// ===========================================================================
// Fused enc4 + enc5 (both CIN=2, 5x5) @256 with fused 2x2 pool -> @128.
// ===========================================================================
__global__ __launch_bounds__(256)
void enc45_fused(const float* __restrict__ inU, const float* __restrict__ inC,
                 const float* __restrict__ wA, const float* __restrict__ bA,
                 const float* __restrict__ wB, const float* __restrict__ bB,
                 float* __restrict__ uout, float* __restrict__ cout,
                 float* __restrict__ poolU, float* __restrict__ poolC)
{
    __shared__ __align__(16) float2 in_cd[2][24][84];
    __shared__ __align__(16) float2 mid_cd[2][20][72];

    const int tid = threadIdx.x;
    const int bw = blockIdx.x * 64;
    const int bh = blockIdx.y * 16;
    const int b  = blockIdx.z;

    const float4* U4 = (const float4*)inU;
    const float4* C4 = (const float4*)inC;
    for (int i = tid; i < 960; i += 256) {
        const int ci = i / 480;
        const int r = (i / 20) % 24, k = i % 20;
        const int gh = bh - 4 + r;
        const int gw4 = (bw >> 2) - 2 + k;
        float4 dd = make_float4(0.f, 0.f, 0.f, 0.f);
        float4 cc = make_float4(0.f, 0.f, 0.f, 0.f);
        if ((unsigned)gh < 256u && (unsigned)gw4 < 64u) {
            const int a = ((b * 2 + ci) << 14) + (gh << 6) + gw4;
            dd = U4[a];
            cc = C4[a];
        }
        float4* dst = (float4*)&in_cd[ci][r][4 * k];
        dst[0] = make_float4(cc.x, dd.x, cc.y, dd.y);
        dst[1] = make_float4(cc.z, dd.z, cc.w, dd.w);
    }

    float isA0, isA1;
    {
        float s0 = 0.f, s1 = 0.f;
        for (int i = 0; i < 50; ++i) { s0 += wA[i]; s1 += wA[50 + i]; }
        isA0 = 1.0f / s0;
        isA1 = 1.0f / s1;
    }
    __syncthreads();

    // Stage A: 20 rows x 18 groups = 360 items (256 + 104), CIN=2.
    #pragma unroll
    for (int pass = 0; pass < 2; ++pass) {
        int r, g;
        bool active = true;
        if (pass == 0) { r = tid >> 4; g = tid & 15; }
        else {
            if (tid < 64) { r = 16 + (tid >> 4); g = tid & 15; }
            else if (tid < 104) { const int t = tid - 64; r = t >> 1; g = 16 + (t & 1); }
            else { active = false; r = 0; g = 0; }
        }
        if (active) {
            v2f acc[2][4];
            #pragma unroll
            for (int c = 0; c < 2; ++c)
                #pragma unroll
                for (int p = 0; p < 4; ++p) acc[c][p] = (v2f){0.f, 0.f};
            #pragma unroll
            for (int kh = 0; kh < 5; ++kh) {
                #pragma unroll
                for (int ci = 0; ci < 2; ++ci) {
                    const CD8 cd = load_cd8(&in_cd[ci][r + kh][4 * g + 2]);
                    #pragma unroll
                    for (int kw = 0; kw < 5; ++kw) {
                        const float w0 = wA[((0 * 2 + ci) * 5 + kh) * 5 + kw];
                        const float w1 = wA[((1 * 2 + ci) * 5 + kh) * 5 + kw];
                        #pragma unroll
                        for (int p = 0; p < 4; ++p) {
                            fma2(acc[0][p], w0, cd.v[p + kw]);
                            fma2(acc[1][p], w1, cd.v[p + kw]);
                        }
                    }
                }
            }
            const int orow = bh + r - 2;
            const bool rok = (unsigned)orow < 256u;
            #pragma unroll
            for (int c = 0; c < 2; ++c) {
                const float is = (c == 0) ? isA0 : isA1;
                float cv[4], du[4];
                #pragma unroll
                for (int p = 0; p < 4; ++p) {
                    const int ocol = bw + 4 * g - 4 + p;
                    const bool ok = rok && (unsigned)ocol < 256u;
                    const float xo = acc[c][p].y * frcp(acc[c][p].x + EPSF) + bA[c];
                    const float v = acc[c][p].x * is;
                    cv[p] = ok ? v : 0.f;
                    du[p] = ok ? xo * v : 0.f;
                }
                float4* dst = (float4*)&mid_cd[c][r][4 * g];
                dst[0] = make_float4(cv[0], du[0], cv[1], du[1]);
                dst[1] = make_float4(cv[2], du[2], cv[3], du[3]);
            }
        }
    }
    __syncthreads();

    // Stage B + pool.
    const int lh = tid >> 4;
    const int lw = (tid & 15) << 2;
    v2f acc[2][4];
    #pragma unroll
    for (int c = 0; c < 2; ++c)
        #pragma unroll
        for (int p = 0; p < 4; ++p) acc[c][p] = (v2f){0.f, 0.f};

    conv_core_i<2, 0, 2, 5, 20>(&mid_cd[0][0][0], wB, lh, lw, acc);

    float4 uo[2], co4[2];
    nconv_epilogue_i<2, 5>(wB, bB, acc, uo, co4);

    const int oh = bh + lh;
    #pragma unroll
    for (int c = 0; c < 2; ++c) {
        const int a = ((b * 2 + c) << 14) + (oh << 6) + ((bw + lw) >> 2);
        ((float4*)uout)[a] = uo[c];
        ((float4*)cout)[a] = co4[c];
    }

    // Fused 2x2 pool via interleaved overlay on mid_cd: {c, u} per px.
    __syncthreads();
    float2* pb = &mid_cd[0][0][0];   // [2][16][64] float2
    #pragma unroll
    for (int c = 0; c < 2; ++c) {
        float2* row = pb + (c * 16 + lh) * 64 + lw;
        #pragma unroll
        for (int p = 0; p < 4; ++p)
            row[p] = make_float2((&co4[c].x)[p], (&uo[c].x)[p]);
    }
    __syncthreads();
    #pragma unroll
    for (int rep = 0; rep < 2; ++rep) {
        const int o = tid + rep * 256;
        const int ch = o >> 8;
        const int idx = o & 255;
        const int pr = idx >> 5;
        const int pcc = idx & 31;
        const float2* base = pb + (ch * 16 + 2 * pr) * 64 + 2 * pcc;
        const float2 a0 = base[0], a1 = base[1], a2 = base[64], a3 = base[65];
        float m = a0.x, g = a0.y;
        if (a1.x > m) { m = a1.x; g = a1.y; }
        if (a2.x > m) { m = a2.x; g = a2.y; }
        if (a3.x > m) { m = a3.x; g = a3.y; }
        const int pa = ((b * 2 + ch) << 14) + (((bh >> 1) + pr) << 7) + (bw >> 1) + pcc;
        poolU[pa] = g * 0.25f;
        poolC[pa] = m * 0.25f;
    }
}

// ===========================================================================
// Mid kernel: whole @128/@64 sub-net per 64x16 tile @128 (interleaved).
// ===========================================================================
__global__ __launch_bounds__(256)
void mid_kern(const float* __restrict__ p2U, const float* __restrict__ p2C,
              const float* __restrict__ w2, const float* __restrict__ b2,
              const float* __restrict__ w4, const float* __restrict__ b4,
              float* __restrict__ x34U, float* __restrict__ x34C)
{
    __shared__ __align__(16) float2 sp_cd[2][32][88];
    __shared__ __align__(16) float2 sx3_cd[2][28][80];
    __shared__ __align__(16) float2 sp3_cd[2][14][48];
    __shared__ __align__(16) float2 sx4_cd[2][10][40];

    const int tid = threadIdx.x;
    const int bw = blockIdx.x * 64;
    const int bh = blockIdx.y * 16;
    const int b = blockIdx.z;

    const float4* U4 = (const float4*)p2U;
    const float4* C4 = (const float4*)p2C;
    for (int i = tid; i < 2 * 32 * 22; i += 256) {
        const int ci = i / 704;
        const int r  = (i / 22) % 32;
        const int cf = i % 22;
        const int gh = bh - 8 + r;
        const int gw4 = (bw >> 2) - 3 + cf;
        float4 dd = make_float4(0.f, 0.f, 0.f, 0.f);
        float4 cc = make_float4(0.f, 0.f, 0.f, 0.f);
        if ((unsigned)gh < 128u && (unsigned)gw4 < 32u) {
            const int a = ((b * 2 + ci) << 12) + (gh << 5) + gw4;
            dd = U4[a];
            cc = C4[a];
        }
        float4* dst = (float4*)&sp_cd[ci][r][cf * 4];
        dst[0] = make_float4(cc.x, dd.x, cc.y, dd.y);
        dst[1] = make_float4(cc.z, dd.z, cc.w, dd.w);
    }
    __syncthreads();

    {
        float s2[2];
        #pragma unroll
        for (int c = 0; c < 2; ++c) {
            float s = 0.f;
            for (int i = 0; i < 50; ++i) s += w2[c * 50 + i];
            s2[c] = 1.0f / s;
        }
        for (int s = tid; s < 560; s += 256) {
            const int r = s / 20;
            const int g = s % 20;
            v2f acc[2][4];
            #pragma unroll
            for (int c = 0; c < 2; ++c)
                #pragma unroll
                for (int p = 0; p < 4; ++p) acc[c][p] = (v2f){0.f, 0.f};
            #pragma unroll
            for (int kh = 0; kh < 5; ++kh) {
                #pragma unroll
                for (int ci = 0; ci < 2; ++ci) {
                    const CD8 cd = load_cd8(&sp_cd[ci][r + kh][4 * g + 2]);
                    #pragma unroll
                    for (int kw = 0; kw < 5; ++kw) {
                        const float w0 = w2[((0 * 2 + ci) * 5 + kh) * 5 + kw];
                        const float w1 = w2[((1 * 2 + ci) * 5 + kh) * 5 + kw];
                        #pragma unroll
                        for (int p = 0; p < 4; ++p) {
                            fma2(acc[0][p], w0, cd.v[p + kw]);
                            fma2(acc[1][p], w1, cd.v[p + kw]);
                        }
                    }
                }
            }
            const int orow = bh - 6 + r;
            const bool rok = (unsigned)orow < 128u;
            #pragma unroll
            for (int c = 0; c < 2; ++c) {
                float cv[4], du[4];
                #pragma unroll
                for (int p = 0; p < 4; ++p) {
                    const int ocol = bw - 8 + 4 * g + p;
                    const bool ok = rok && (unsigned)ocol < 128u;
                    const float xo = acc[c][p].y * frcp(acc[c][p].x + EPSF) + b2[c];
                    const float v = acc[c][p].x * s2[c];
                    cv[p] = ok ? v : 0.f;
                    du[p] = ok ? xo * v : 0.f;
                }
                float4* dst = (float4*)&sx3_cd[c][r][4 * g];
                dst[0] = make_float4(cv[0], du[0], cv[1], du[1]);
                dst[1] = make_float4(cv[2], du[2], cv[3], du[3]);
            }
        }
    }
    __syncthreads();

    for (int i = tid; i < 2 * 14 * 48; i += 256) {
        const int ch = i / 672;
        const int r  = (i / 48) % 14;
        const int c  = i % 48;
        const int R = (bh >> 1) - 3 + r;
        const int C = (bw >> 1) - 8 + c;
        float g = 0.f, m = 0.f;
        if (c >= 4 && c < 44 && (unsigned)R < 64u && (unsigned)C < 64u) {
            const int xr = 2 * r, xc = 2 * c - 8;
            const float2 a0 = sx3_cd[ch][xr][xc],     a1 = sx3_cd[ch][xr][xc + 1];
            const float2 a2 = sx3_cd[ch][xr + 1][xc], a3 = sx3_cd[ch][xr + 1][xc + 1];
            m = a0.x; g = a0.y;
            if (a1.x > m) { m = a1.x; g = a1.y; }
            if (a2.x > m) { m = a2.x; g = a2.y; }
            if (a3.x > m) { m = a3.x; g = a3.y; }
            g *= 0.25f; m *= 0.25f;
        }
        sp3_cd[ch][r][c] = make_float2(m, g);
    }
    __syncthreads();

    {
        float s2[2];
        #pragma unroll
        for (int c = 0; c < 2; ++c) {
            float s = 0.f;
            for (int i = 0; i < 50; ++i) s += w2[c * 50 + i];
            s2[c] = 1.0f / s;
        }
        for (int s = tid; s < 100; s += 256) {
            const int r = s / 10;
            const int g = s % 10;
            v2f acc[2][4];
            #pragma unroll
            for (int c = 0; c < 2; ++c)
                #pragma unroll
                for (int p = 0; p < 4; ++p) acc[c][p] = (v2f){0.f, 0.f};
            #pragma unroll
            for (int kh = 0; kh < 5; ++kh) {
                #pragma unroll
                for (int ci = 0; ci < 2; ++ci) {
                    const CD8 cd = load_cd8(&sp3_cd[ci][r + kh][4 * g + 2]);
                    #pragma unroll
                    for (int kw = 0; kw < 5; ++kw) {
                        const float w0 = w2[((0 * 2 + ci) * 5 + kh) * 5 + kw];
                        const float w1 = w2[((1 * 2 + ci) * 5 + kh) * 5 + kw];
                        #pragma unroll
                        for (int p = 0; p < 4; ++p) {
                            fma2(acc[0][p], w0, cd.v[p + kw]);
                            fma2(acc[1][p], w1, cd.v[p + kw]);
                        }
                    }
                }
            }
            const int orow = (bh >> 1) - 1 + r;
            const bool rok = (unsigned)orow < 64u;
            #pragma unroll
            for (int c = 0; c < 2; ++c) {
                float cv[4], du[4];
                #pragma unroll
                for (int p = 0; p < 4; ++p) {
                    const int ocol = (bw >> 1) - 4 + 4 * g + p;
                    const bool ok = rok && (unsigned)ocol < 64u;
                    const float xo = acc[c][p].y * frcp(acc[c][p].x + EPSF) + b2[c];
                    const float v = acc[c][p].x * s2[c];
                    cv[p] = ok ? v : 0.f;
                    du[p] = ok ? xo * v : 0.f;
                }
                float4* dst = (float4*)&sx4_cd[c][r][4 * g];
                dst[0] = make_float4(cv[0], du[0], cv[1], du[1]);
                dst[1] = make_float4(cv[2], du[2], cv[3], du[3]);
            }
        }
    }
    __syncthreads();

    {
        const int lh = tid >> 4;
        const int lw = (tid & 15) << 2;
        v2f acc[2][4];
        #pragma unroll
        for (int c = 0; c < 2; ++c)
            #pragma unroll
            for (int p = 0; p < 4; ++p) acc[c][p] = (v2f){0.f, 0.f};

        // skip conv over sx3 (tile row0 = bh-6, col0 = bw-8): taps at px
        // lw+7..lw+13 -> load px [lw+6, lw+14), index j = p+kw+1.
        #pragma unroll
        for (int kh = 0; kh < 3; ++kh) {
            #pragma unroll
            for (int ci = 0; ci < 2; ++ci) {
                const CD8 cd = load_cd8(&sx3_cd[ci][lh + kh + 5][lw + 6]);
                #pragma unroll
                for (int kw = 0; kw < 3; ++kw) {
                    const float w0 = w4[((0 * 4 + ci) * 3 + kh) * 3 + kw];
                    const float w1 = w4[((1 * 4 + ci) * 3 + kh) * 3 + kw];
                    #pragma unroll
                    for (int p = 0; p < 4; ++p) {
                        const int j = p + kw + 1;
                        fma2(acc[0][p], w0, cd.v[j]);
                        fma2(acc[1][p], w1, cd.v[j]);
                    }
                }
            }
        }
        conv_low_i<2>(&sx4_cd[0][0][0], w4, lh, lw, acc);

        float4 uo[2], co4[2];
        nconv_epilogue_i<4, 3>(w4, b4, acc, uo, co4);
        #pragma unroll
        for (int c = 0; c < 2; ++c) {
            const int a = ((b * 2 + c) << 12) + ((bh + lh) << 5) + ((bw + lw) >> 2);
            ((float4*)x34U)[a] = uo[c];
            ((float4*)x34C)[a] = co4[c];
        }
    }
}

// ===========================================================================
// Tiled nconv (enc3 @512 + pool), interleaved.
// ===========================================================================
template<int CIN, int K, int LOGHW, bool IN_IS_U, bool POOL>
__global__ __launch_bounds__(256)
void nconv_tiled(const float* __restrict__ xin, const float* __restrict__ cin_,
                 const float* __restrict__ wgt, const float* __restrict__ bias,
                 float* __restrict__ uout, float* __restrict__ cout,
                 float* __restrict__ poolU, float* __restrict__ poolC)
{
    constexpr int HW = 1 << LOGHW;
    constexpr int PAD = K / 2;
    constexpr int TH = 16;
    constexpr int ROWS = TH + 2 * PAD;
    constexpr int NC4 = 18;
    __shared__ __align__(16) float2 s_cd[CIN][ROWS][72];

    const int tid = threadIdx.x;
    const int base_w = blockIdx.x * 64;
    const int base_h = blockIdx.y * TH;
    const int b = blockIdx.z;

    constexpr int SLOTS = CIN * ROWS * NC4;
    const float4* x4 = (const float4*)xin;
    const float4* c4p = (const float4*)cin_;
    for (int i = tid; i < SLOTS; i += 256) {
        const int ci = i / (ROWS * NC4);
        const int r  = (i / NC4) % ROWS;
        const int cf = i % NC4;
        const int gh = base_h - PAD + r;
        const int gw4 = (base_w >> 2) + cf - 1;
        float4 dd = make_float4(0.f, 0.f, 0.f, 0.f);
        float4 cc = make_float4(0.f, 0.f, 0.f, 0.f);
        if ((unsigned)gh < (unsigned)HW && (unsigned)gw4 < (unsigned)(HW >> 2)) {
            const int a = ((b * CIN + ci) << (2 * LOGHW - 2)) + (gh << (LOGHW - 2)) + gw4;
            const float4 xx = x4[a];
            cc = c4p[a];
            if (IN_IS_U) dd = xx;
            else dd = make_float4(xx.x * cc.x, xx.y * cc.y, xx.z * cc.z, xx.w * cc.w);
        }
        float4* dst = (float4*)&s_cd[ci][r][cf * 4];
        dst[0] = make_float4(cc.x, dd.x, cc.y, dd.y);
        dst[1] = make_float4(cc.z, dd.z, cc.w, dd.w);
    }
    __syncthreads();

    const int lh = tid >> 4;
    const int lw = (tid & 15) << 2;
    v2f acc[2][4];
    #pragma unroll
    for (int c = 0; c < 2; ++c)
        #pragma unroll
        for (int p = 0; p < 4; ++p) acc[c][p] = (v2f){0.f, 0.f};

    conv_core_i<CIN, 0, CIN, K, ROWS>(&s_cd[0][0][0], wgt, lh, lw, acc);

    float4 uo[2], co4[2];
    nconv_epilogue_i<CIN, K>(wgt, bias, acc, uo, co4);

    const int oh = base_h + lh;
    #pragma unroll
    for (int c = 0; c < 2; ++c) {
        const int a = ((b * 2 + c) << (2 * LOGHW - 2)) + (oh << (LOGHW - 2)) + ((base_w + lw) >> 2);
        ((float4*)uout)[a] = uo[c];
        ((float4*)cout)[a] = co4[c];
    }

    if (POOL) {
        __syncthreads();
        float2* pb = &s_cd[0][0][0];   // [2][16][64] float2
        #pragma unroll
        for (int c = 0; c < 2; ++c) {
            float2* row = pb + (c * 16 + lh) * 64 + lw;
            #pragma unroll
            for (int p = 0; p < 4; ++p)
                row[p] = make_float2((&co4[c].x)[p], (&uo[c].x)[p]);
        }
        __syncthreads();
        #pragma unroll
        for (int rep = 0; rep < 2; ++rep) {
            const int o = tid + rep * 256;
            const int ch = o >> 8;
            const int idx = o & 255;
            const int pr = idx >> 5;
            const int pcc = idx & 31;
            const float2* base = pb + (ch * 16 + 2 * pr) * 64 + 2 * pcc;
            const float2 a0 = base[0], a1 = base[1], a2 = base[64], a3 = base[65];
            float m = a0.x, g = a0.y;
            if (a1.x > m) { m = a1.x; g = a1.y; }
            if (a2.x > m) { m = a2.x; g = a2.y; }
            if (a3.x > m) { m = a3.x; g = a3.y; }
            const int pa = ((b * 2 + ch) << (2 * (LOGHW - 1)))
                         + (((base_h >> 1) + pr) << (LOGHW - 1)) + (base_w >> 1) + pcc;
            poolU[pa] = g * 0.25f;
            poolC[pa] = m * 0.25f;
        }
    }
}

// ===========================================================================
// Decoder cat-nconv, interleaved; optional fused final 1x1 -> d_out.
// ===========================================================================
template<bool UP_FIRST, int LOGHW, bool FINAL>
__global__ __launch_bounds__(256)
void nconv_cat_tiled(const float* __restrict__ skU, const float* __restrict__ skC,
                     const float* __restrict__ loU, const float* __restrict__ loC,
                     const float* __restrict__ wgt, const float* __restrict__ bias,
                     float* __restrict__ uout, float* __restrict__ cout,
                     const float* __restrict__ w7, const float* __restrict__ b7)
{
    constexpr int HW = 1 << LOGHW;
    constexpr int HWL = HW >> 1;
    constexpr int TH = 16;
    constexpr int ROWS = TH + 2;
    constexpr int NC4 = 18;
    constexpr int SK0 = UP_FIRST ? 2 : 0;
    constexpr int LO0 = UP_FIRST ? 0 : 2;
    __shared__ __align__(16) float2 s_cd[2][ROWS][72];
    __shared__ __align__(16) float2 lo_cd[2][10][40];

    const int tid = threadIdx.x;
    const int base_w = blockIdx.x * 64;
    const int base_h = blockIdx.y * TH;
    const int b = blockIdx.z;

    constexpr int SLOTS = 2 * ROWS * NC4;
    const float4* sU4 = (const float4*)skU;
    const float4* sC4 = (const float4*)skC;
    for (int i = tid; i < SLOTS; i += 256) {
        const int ci = i / (ROWS * NC4);
        const int r  = (i / NC4) % ROWS;
        const int cf = i % NC4;
        const int gh = base_h - 1 + r;
        const int gw4 = (base_w >> 2) + cf - 1;
        float4 dd = make_float4(0.f, 0.f, 0.f, 0.f);
        float4 cc = make_float4(0.f, 0.f, 0.f, 0.f);
        if ((unsigned)gh < (unsigned)HW && (unsigned)gw4 < (unsigned)(HW >> 2)) {
            const int a = ((b * 2 + ci) << (2 * LOGHW - 2)) + (gh << (LOGHW - 2)) + gw4;
            dd = sU4[a];
            cc = sC4[a];
        }
        float4* dst = (float4*)&s_cd[ci][r][cf * 4];
        dst[0] = make_float4(cc.x, dd.x, cc.y, dd.y);
        dst[1] = make_float4(cc.z, dd.z, cc.w, dd.w);
    }
    constexpr int LO_SLOTS = 2 * 10 * 10;
    const int lo_r0 = (base_h >> 1) - 1;
    const int lo_c4_0 = (base_w >> 3) - 1;
    const float4* lU4 = (const float4*)loU;
    const float4* lC4 = (const float4*)loC;
    for (int i = tid; i < LO_SLOTS; i += 256) {
        const int ci = i / 100;
        const int r  = (i / 10) % 10;
        const int cf = i % 10;
        const int gr = lo_r0 + r;
        const int gc4 = lo_c4_0 + cf;
        float4 dd = make_float4(0.f, 0.f, 0.f, 0.f);
        float4 cc = make_float4(0.f, 0.f, 0.f, 0.f);
        if ((unsigned)gr < (unsigned)HWL && (unsigned)gc4 < (unsigned)(HWL >> 2)) {
            const int a = ((b * 2 + ci) << (2 * (LOGHW - 1) - 2)) + (gr << (LOGHW - 3)) + gc4;
            dd = lU4[a];
            cc = lC4[a];
        }
        float4* dst = (float4*)&lo_cd[ci][r][cf * 4];
        dst[0] = make_float4(cc.x, dd.x, cc.y, dd.y);
        dst[1] = make_float4(cc.z, dd.z, cc.w, dd.w);
    }
    __syncthreads();

    const int lh = tid >> 4;
    const int lw = (tid & 15) << 2;
    v2f acc[2][4];
    #pragma unroll
    for (int c = 0; c < 2; ++c)
        #pragma unroll
        for (int p = 0; p < 4; ++p) acc[c][p] = (v2f){0.f, 0.f};

    conv_core_i<2, SK0, 4, 3, ROWS>(&s_cd[0][0][0], wgt, lh, lw, acc);
    conv_low_i<LO0>(&lo_cd[0][0][0], wgt, lh, lw, acc);

    float4 uo[2], co4[2];
    nconv_epilogue_i<4, 3>(wgt, bias, acc, uo, co4);

    const int oh = base_h + lh;
    if (FINAL) {
        const float w70 = w7[0], w71 = w7[1], bb7 = b7[0];
        const float inv = frcp(w70 + w71);
        float4 xo4, cc4;
        #pragma unroll
        for (int p = 0; p < 4; ++p) {
            const float d1 = w70 * (&co4[0].x)[p] + w71 * (&co4[1].x)[p];
            (&xo4.x)[p] = (w70 * (&uo[0].x)[p] + w71 * (&uo[1].x)[p]) * frcp(d1 + EPSF) + bb7;
            (&cc4.x)[p] = d1 * inv;
        }
        const int a = (b << (2 * LOGHW - 2)) + (oh << (LOGHW - 2)) + ((base_w + lw) >> 2);
        ((float4*)uout)[a] = xo4;
        ((float4*)uout)[(1 << 19) + a] = cc4;
    } else {
        #pragma unroll
        for (int c = 0; c < 2; ++c) {
            const int a = ((b * 2 + c) << (2 * LOGHW - 2)) + (oh << (LOGHW - 2)) + ((base_w + lw) >> 2);
            ((float4*)uout)[a] = uo[c];
            ((float4*)cout)[a] = co4[c];
        }
    }
}

// ---------------------------------------------------------------------------
extern "C" void kernel_launch(void* const* d_in, const int* in_sizes, int n_in,
                              void* d_out, int out_size, void* d_ws, size_t ws_size,
                              hipStream_t stream) {
    (void)in_sizes; (void)n_in; (void)out_size; (void)ws_size;
    const float* x0 = (const float*)d_in[0];
    const float* c0 = (const float*)d_in[1];
    const float* w1 = (const float*)d_in[2];  const float* b1 = (const float*)d_in[3];
    const float* w2 = (const float*)d_in[4];  const float* b2 = (const float*)d_in[5];
    const float* w3 = (const float*)d_in[6];  const float* b3 = (const float*)d_in[7];
    const float* w4 = (const float*)d_in[8];  const float* b4 = (const float*)d_in[9];
    const float* w5 = (const float*)d_in[10]; const float* b5 = (const float*)d_in[11];
    const float* w6 = (const float*)d_in[12]; const float* b6 = (const float*)d_in[13];
    const float* w7 = (const float*)d_in[14]; const float* b7 = (const float*)d_in[15];

    float* ws = (float*)d_ws;
    const size_t S512 = 8ull * 2 * 512 * 512;
    const size_t S256 = 8ull * 2 * 256 * 256;
    const size_t S128 = 8ull * 2 * 128 * 128;

    float* X1x = ws;            float* X1c = ws + S512;
    float* Ax  = ws + 2 * S512;
    float* Bx  = ws + 4 * S512; float* Bc  = ws + 5 * S512;
    float* x23x = Ax;               float* x23c = Ax + S256;
    float* x2x  = Ax + 2 * S256;    float* x2c  = Ax + 3 * S256;
    float* p1x  = Ax + 4 * S256;    float* p1c  = Ax + 5 * S256;
    float* p2x  = Bx + 2 * S128;    float* p2c  = Bx + 3 * S128;
    float* x34x = Bx + 4 * S128;    float* x34c = Bx + 5 * S128;

    // K1: fused enc1+enc2 @512 -> B
    enc12_fused<<<dim3(8, 32, 8), 256, 0, stream>>>(
        x0, c0, w1, b1, w2, b2, Bx, Bc);
    // K2: enc3 @512 + pool -> X1 (skip), p1 @256
    nconv_tiled<2, 5, 9, true, true><<<dim3(8, 32, 8), 256, 0, stream>>>(
        Bx, Bc, w3, b3, X1x, X1c, p1x, p1c);
    // K3: fused enc4+enc5 @256 + pool -> x2 @256, p2 @128
    // (p2/x34 overlay B's tail region; B is consumed by K2 first.)
    enc45_fused<<<dim3(4, 16, 8), 256, 0, stream>>>(
        p1x, p1c, w2, b2, w3, b3, x2x, x2c, p2x, p2c);
    // K4: whole @128/@64 sub-net -> x34 @128
    mid_kern<<<dim3(2, 8, 8), 256, 0, stream>>>(
        p2x, p2c, w2, b2, w4, b4, x34x, x34c);
    // K5: cat @256 -> x23
    nconv_cat_tiled<false, 8, false><<<dim3(4, 16, 8), 256, 0, stream>>>(
        x2x, x2c, x34x, x34c, w5, b5, x23x, x23c, nullptr, nullptr);
    // K6: cat @512 + final 1x1 -> d_out
    nconv_cat_tiled<true, 9, true><<<dim3(8, 32, 8), 256, 0, stream>>>(
        X1x, X1c, x23x, x23c, w6, b6, (float*)d_out, nullptr, w7, b7);
}